// Round 1
// baseline (1147.808 us; speedup 1.0000x reference)
//
#include <hip/hip_runtime.h>

#define N_NODES 50000
#define N_EDGES 800000
#define EMB 100
#define NORM_EPS 1e-12f

// out[row] += val * x[col], one (edge, feature) pair per thread.
// 128 threads cover the 100 features of one edge (f in [0,128), f<100 active).
__global__ void spmm_atomic(const int* __restrict__ adj_row,
                            const int* __restrict__ adj_col,
                            const float* __restrict__ adj_val,
                            const float* __restrict__ x,
                            float* __restrict__ y) {
    long long tid = (long long)blockIdx.x * blockDim.x + threadIdx.x;
    int e = (int)(tid >> 7);
    int f = (int)(tid & 127);
    if (e >= N_EDGES || f >= EMB) return;
    int c = adj_col[e];
    int r = adj_row[e];
    float v = adj_val[e];
    atomicAdd(&y[(long long)r * EMB + f], v * x[(long long)c * EMB + f]);
}

// One wave (64 lanes) per node: compute ||x_row||_2, then
// out_row (+)= a[l] * x_row / max(norm, eps).
// lane i handles features i and i+64 (i+64 < 100 for i < 36).
__global__ void norm_add(const float* __restrict__ x,
                         const float* __restrict__ a,
                         int l, int first,
                         float* __restrict__ out) {
    int wave = blockIdx.x * (blockDim.x >> 6) + (threadIdx.x >> 6);
    int lane = threadIdx.x & 63;
    if (wave >= N_NODES) return;
    const float* xr = x + (long long)wave * EMB;
    float v0 = (lane < EMB) ? xr[lane] : 0.0f;
    float v1 = (lane + 64 < EMB) ? xr[lane + 64] : 0.0f;
    float s = v0 * v0 + v1 * v1;
    // full-wave butterfly reduction (64 lanes)
    #pragma unroll
    for (int off = 32; off > 0; off >>= 1) s += __shfl_xor(s, off);
    float norm = sqrtf(s);
    float scale = a[l] / fmaxf(norm, NORM_EPS);
    float* orow = out + (long long)wave * EMB;
    if (lane < EMB) {
        float r = v0 * scale;
        if (!first) r += orow[lane];
        orow[lane] = r;
    }
    if (lane + 64 < EMB) {
        float r = v1 * scale;
        if (!first) r += orow[lane + 64];
        orow[lane + 64] = r;
    }
}

extern "C" void kernel_launch(void* const* d_in, const int* in_sizes, int n_in,
                              void* d_out, int out_size, void* d_ws, size_t ws_size,
                              hipStream_t stream) {
    const int*   adj_row   = (const int*)d_in[0];
    const int*   adj_col   = (const int*)d_in[1];
    const float* adj_val   = (const float*)d_in[2];
    const float* embedding = (const float*)d_in[3];
    const float* a         = (const float*)d_in[4];
    float* out = (float*)d_out;

    float* buf0 = (float*)d_ws;
    float* buf1 = buf0 + (size_t)N_NODES * EMB;
    float* bufs[2] = {buf0, buf1};

    const int norm_blocks = (N_NODES + 3) / 4;  // 4 waves per 256-thread block

    // layer 0: out = a[0] * normalize(embedding)
    norm_add<<<norm_blocks, 256, 0, stream>>>(embedding, a, 0, 1, out);

    const float* xcur = embedding;
    for (int l = 1; l <= 3; ++l) {
        float* y = bufs[(l - 1) & 1];
        hipMemsetAsync(y, 0, sizeof(float) * (size_t)N_NODES * EMB, stream);
        long long total = (long long)N_EDGES * 128;
        int blocks = (int)(total / 256);
        spmm_atomic<<<blocks, 256, 0, stream>>>(adj_row, adj_col, adj_val, xcur, y);
        norm_add<<<norm_blocks, 256, 0, stream>>>(y, a, l, 0, out);
        xcur = y;
    }
}

// Round 2
// 523.310 us; speedup vs baseline: 2.1934x; 2.1934x over previous
//
#include <hip/hip_runtime.h>

#define N_NODES 50000
#define N_EDGES 800000
#define EMB 100
#define NORM_EPS 1e-12f
#define SCAN_THREADS 1024

__global__ void count_deg(const int* __restrict__ adj_row, int* __restrict__ deg) {
    int e = blockIdx.x * blockDim.x + threadIdx.x;
    if (e < N_EDGES) atomicAdd(&deg[adj_row[e]], 1);
}

// Single-block exclusive scan of deg -> row_ptr (and a scatter cursor copy).
__global__ void scan_rowptr(const int* __restrict__ deg, int* __restrict__ row_ptr,
                            int* __restrict__ cursor) {
    __shared__ int partial[SCAN_THREADS];
    const int t = threadIdx.x;
    const int C = (N_NODES + SCAN_THREADS - 1) / SCAN_THREADS;  // 49
    const int base = t * C;
    int sum = 0;
    for (int i = 0; i < C; ++i) {
        int idx = base + i;
        if (idx < N_NODES) sum += deg[idx];
    }
    partial[t] = sum;
    __syncthreads();
    // Hillis-Steele inclusive scan over 1024 partials
    for (int off = 1; off < SCAN_THREADS; off <<= 1) {
        int v = (t >= off) ? partial[t - off] : 0;
        __syncthreads();
        partial[t] += v;
        __syncthreads();
    }
    int run = (t == 0) ? 0 : partial[t - 1];
    for (int i = 0; i < C; ++i) {
        int idx = base + i;
        if (idx < N_NODES) {
            row_ptr[idx] = run;
            cursor[idx]  = run;
            run += deg[idx];
        }
    }
    if (t == SCAN_THREADS - 1) row_ptr[N_NODES] = run;
}

__global__ void scatter_csr(const int* __restrict__ adj_row, const int* __restrict__ adj_col,
                            const float* __restrict__ adj_val, int* __restrict__ cursor,
                            int* __restrict__ csr_col, float* __restrict__ csr_val) {
    int e = blockIdx.x * blockDim.x + threadIdx.x;
    if (e < N_EDGES) {
        int r = adj_row[e];
        int p = atomicAdd(&cursor[r], 1);
        csr_col[p] = adj_col[e];
        csr_val[p] = adj_val[e];
    }
}

// One wave per destination node; lane < 50 holds a float2 (features 2*lane, 2*lane+1).
// Atomic-free: accumulate in registers, one store at the end.
__global__ void spmm_csr(const int* __restrict__ row_ptr, const int* __restrict__ csr_col,
                         const float* __restrict__ csr_val, const float* __restrict__ x,
                         float* __restrict__ y) {
    int wave = blockIdx.x * (blockDim.x >> 6) + (threadIdx.x >> 6);
    int lane = threadIdx.x & 63;
    if (wave >= N_NODES) return;
    int start = row_ptr[wave];
    int end   = row_ptr[wave + 1];
    const float2* x2 = (const float2*)x;
    float ax = 0.0f, ay = 0.0f;
    int e = start;
    for (; e + 1 < end; e += 2) {
        int c0 = csr_col[e];     float v0 = csr_val[e];
        int c1 = csr_col[e + 1]; float v1 = csr_val[e + 1];
        if (lane < 50) {
            float2 a0 = x2[(long long)c0 * 50 + lane];
            float2 a1 = x2[(long long)c1 * 50 + lane];
            ax += v0 * a0.x; ay += v0 * a0.y;
            ax += v1 * a1.x; ay += v1 * a1.y;
        }
    }
    if (e < end) {
        int c = csr_col[e]; float v = csr_val[e];
        if (lane < 50) {
            float2 a0 = x2[(long long)c * 50 + lane];
            ax += v * a0.x; ay += v * a0.y;
        }
    }
    if (lane < 50) {
        float2 r; r.x = ax; r.y = ay;
        ((float2*)y)[(long long)wave * 50 + lane] = r;
    }
}

// One wave per node: out_row (+)= a[l] * x_row / max(||x_row||, eps).
__global__ void norm_add(const float* __restrict__ x, const float* __restrict__ a,
                         int l, int first, float* __restrict__ out) {
    int wave = blockIdx.x * (blockDim.x >> 6) + (threadIdx.x >> 6);
    int lane = threadIdx.x & 63;
    if (wave >= N_NODES) return;
    const float* xr = x + (long long)wave * EMB;
    float v0 = (lane < EMB) ? xr[lane] : 0.0f;
    float v1 = (lane + 64 < EMB) ? xr[lane + 64] : 0.0f;
    float s = v0 * v0 + v1 * v1;
    #pragma unroll
    for (int off = 32; off > 0; off >>= 1) s += __shfl_xor(s, off);
    float norm = sqrtf(s);
    float scale = a[l] / fmaxf(norm, NORM_EPS);
    float* orow = out + (long long)wave * EMB;
    if (lane < EMB) {
        float r = v0 * scale;
        if (!first) r += orow[lane];
        orow[lane] = r;
    }
    if (lane + 64 < EMB) {
        float r = v1 * scale;
        if (!first) r += orow[lane + 64];
        orow[lane + 64] = r;
    }
}

extern "C" void kernel_launch(void* const* d_in, const int* in_sizes, int n_in,
                              void* d_out, int out_size, void* d_ws, size_t ws_size,
                              hipStream_t stream) {
    const int*   adj_row   = (const int*)d_in[0];
    const int*   adj_col   = (const int*)d_in[1];
    const float* adj_val   = (const float*)d_in[2];
    const float* embedding = (const float*)d_in[3];
    const float* a         = (const float*)d_in[4];
    float* out = (float*)d_out;

    // workspace layout (all offsets in elements; float2-aligned)
    float* buf0    = (float*)d_ws;                               // 5,000,000 f
    float* buf1    = buf0 + (size_t)N_NODES * EMB;               // 5,000,000 f
    float* csr_val = buf1 + (size_t)N_NODES * EMB;               // 800,000 f
    int*   csr_col = (int*)(csr_val + N_EDGES);                  // 800,000 i
    int*   row_ptr = csr_col + N_EDGES;                          // 50,001 i
    int*   cursor  = row_ptr + (N_NODES + 1);                    // 50,000 i
    int*   deg     = cursor + N_NODES;                           // 50,000 i
    float* bufs[2] = {buf0, buf1};

    const int edge_blocks = (N_EDGES + 255) / 256;
    const int norm_blocks = (N_NODES + 3) / 4;   // 4 waves / 256-thread block
    const int spmm_blocks = (N_NODES + 3) / 4;

    // ---- CSR build (runs every launch; inputs are re-pristine each call) ----
    hipMemsetAsync(deg, 0, sizeof(int) * N_NODES, stream);
    count_deg<<<edge_blocks, 256, 0, stream>>>(adj_row, deg);
    scan_rowptr<<<1, SCAN_THREADS, 0, stream>>>(deg, row_ptr, cursor);
    scatter_csr<<<edge_blocks, 256, 0, stream>>>(adj_row, adj_col, adj_val,
                                                 cursor, csr_col, csr_val);

    // ---- layer 0: out = a[0] * normalize(embedding) ----
    norm_add<<<norm_blocks, 256, 0, stream>>>(embedding, a, 0, 1, out);

    const float* xcur = embedding;
    for (int l = 1; l <= 3; ++l) {
        float* y = bufs[(l - 1) & 1];
        spmm_csr<<<spmm_blocks, 256, 0, stream>>>(row_ptr, csr_col, csr_val, xcur, y);
        norm_add<<<norm_blocks, 256, 0, stream>>>(y, a, l, 0, out);
        xcur = y;
    }
}

// Round 3
// 406.899 us; speedup vs baseline: 2.8209x; 1.2861x over previous
//
#include <hip/hip_runtime.h>

#define N_NODES 50000
#define N_EDGES 800000
#define EMB 100
#define NORM_EPS 1e-12f
#define SCAN_BLK 256
#define N_SCAN_BLOCKS ((N_NODES + SCAN_BLK - 1) / SCAN_BLK)   // 196

__global__ void count_deg(const int* __restrict__ adj_row, int* __restrict__ deg) {
    int e = blockIdx.x * blockDim.x + threadIdx.x;
    if (e < N_EDGES) atomicAdd(&deg[adj_row[e]], 1);
}

// Stage A: intra-block exclusive scan of deg -> part (exclusive within block),
// and per-block total -> bsum[blockIdx].
__global__ void scan_stageA(const int* __restrict__ deg, int* __restrict__ part,
                            int* __restrict__ bsum) {
    __shared__ int s[SCAN_BLK];
    int t = threadIdx.x;
    int gid = blockIdx.x * SCAN_BLK + t;
    int v = (gid < N_NODES) ? deg[gid] : 0;
    s[t] = v;
    __syncthreads();
    #pragma unroll
    for (int off = 1; off < SCAN_BLK; off <<= 1) {
        int n = (t >= off) ? s[t - off] : 0;
        __syncthreads();
        s[t] += n;
        __syncthreads();
    }
    int incl = s[t];
    if (gid < N_NODES) part[gid] = incl - v;       // exclusive
    if (t == SCAN_BLK - 1) bsum[blockIdx.x] = incl; // block total
}

// Stage B: single tiny block scans bsum[0..195] exclusive -> boff[0..195],
// boff[196] = grand total.
__global__ void scan_stageB(int* __restrict__ bsum, int* __restrict__ boff) {
    __shared__ int s[SCAN_BLK];
    int t = threadIdx.x;
    int v = (t < N_SCAN_BLOCKS) ? bsum[t] : 0;
    s[t] = v;
    __syncthreads();
    #pragma unroll
    for (int off = 1; off < SCAN_BLK; off <<= 1) {
        int n = (t >= off) ? s[t - off] : 0;
        __syncthreads();
        s[t] += n;
        __syncthreads();
    }
    if (t < N_SCAN_BLOCKS) boff[t] = s[t] - v;
    if (t == N_SCAN_BLOCKS - 1) boff[N_SCAN_BLOCKS] = s[t];
}

// Stage C: add block offsets, emit row_ptr + scatter cursor.
__global__ void scan_stageC(const int* __restrict__ part, const int* __restrict__ boff,
                            int* __restrict__ row_ptr, int* __restrict__ cursor) {
    int gid = blockIdx.x * SCAN_BLK + threadIdx.x;
    if (gid < N_NODES) {
        int rp = part[gid] + boff[blockIdx.x];
        row_ptr[gid] = rp;
        cursor[gid]  = rp;
    }
    if (gid == 0) row_ptr[N_NODES] = boff[N_SCAN_BLOCKS];
}

__global__ void scatter_csr(const int* __restrict__ adj_row, const int* __restrict__ adj_col,
                            const float* __restrict__ adj_val, int* __restrict__ cursor,
                            int* __restrict__ csr_col, float* __restrict__ csr_val) {
    int e = blockIdx.x * blockDim.x + threadIdx.x;
    if (e < N_EDGES) {
        int r = adj_row[e];
        int p = atomicAdd(&cursor[r], 1);
        csr_col[p] = adj_col[e];
        csr_val[p] = adj_val[e];
    }
}

// One wave per destination node; lane < 50 holds a float2 (features 2*lane, 2*lane+1).
__global__ void spmm_csr(const int* __restrict__ row_ptr, const int* __restrict__ csr_col,
                         const float* __restrict__ csr_val, const float* __restrict__ x,
                         float* __restrict__ y) {
    int wave = blockIdx.x * (blockDim.x >> 6) + (threadIdx.x >> 6);
    int lane = threadIdx.x & 63;
    if (wave >= N_NODES) return;
    int start = row_ptr[wave];
    int end   = row_ptr[wave + 1];
    const float2* x2 = (const float2*)x;
    float ax = 0.0f, ay = 0.0f;
    int e = start;
    for (; e + 1 < end; e += 2) {
        int c0 = csr_col[e];     float v0 = csr_val[e];
        int c1 = csr_col[e + 1]; float v1 = csr_val[e + 1];
        if (lane < 50) {
            float2 a0 = x2[(long long)c0 * 50 + lane];
            float2 a1 = x2[(long long)c1 * 50 + lane];
            ax += v0 * a0.x; ay += v0 * a0.y;
            ax += v1 * a1.x; ay += v1 * a1.y;
        }
    }
    if (e < end) {
        int c = csr_col[e]; float v = csr_val[e];
        if (lane < 50) {
            float2 a0 = x2[(long long)c * 50 + lane];
            ax += v * a0.x; ay += v * a0.y;
        }
    }
    if (lane < 50) {
        float2 r; r.x = ax; r.y = ay;
        ((float2*)y)[(long long)wave * 50 + lane] = r;
    }
}

// One wave per node: out_row (+)= a[l] * x_row / max(||x_row||, eps).
__global__ void norm_add(const float* __restrict__ x, const float* __restrict__ a,
                         int l, int first, float* __restrict__ out) {
    int wave = blockIdx.x * (blockDim.x >> 6) + (threadIdx.x >> 6);
    int lane = threadIdx.x & 63;
    if (wave >= N_NODES) return;
    const float* xr = x + (long long)wave * EMB;
    float v0 = (lane < EMB) ? xr[lane] : 0.0f;
    float v1 = (lane + 64 < EMB) ? xr[lane + 64] : 0.0f;
    float s = v0 * v0 + v1 * v1;
    #pragma unroll
    for (int off = 32; off > 0; off >>= 1) s += __shfl_xor(s, off);
    float norm = sqrtf(s);
    float scale = a[l] / fmaxf(norm, NORM_EPS);
    float* orow = out + (long long)wave * EMB;
    if (lane < EMB) {
        float r = v0 * scale;
        if (!first) r += orow[lane];
        orow[lane] = r;
    }
    if (lane + 64 < EMB) {
        float r = v1 * scale;
        if (!first) r += orow[lane + 64];
        orow[lane + 64] = r;
    }
}

extern "C" void kernel_launch(void* const* d_in, const int* in_sizes, int n_in,
                              void* d_out, int out_size, void* d_ws, size_t ws_size,
                              hipStream_t stream) {
    const int*   adj_row   = (const int*)d_in[0];
    const int*   adj_col   = (const int*)d_in[1];
    const float* adj_val   = (const float*)d_in[2];
    const float* embedding = (const float*)d_in[3];
    const float* a         = (const float*)d_in[4];
    float* out = (float*)d_out;

    // workspace layout (elements)
    float* buf0    = (float*)d_ws;                               // 5,000,000 f
    float* buf1    = buf0 + (size_t)N_NODES * EMB;               // 5,000,000 f
    float* csr_val = buf1 + (size_t)N_NODES * EMB;               // 800,000 f
    int*   csr_col = (int*)(csr_val + N_EDGES);                  // 800,000 i
    int*   row_ptr = csr_col + N_EDGES;                          // 50,001 i
    int*   cursor  = row_ptr + (N_NODES + 1);                    // 50,000 i
    int*   deg     = cursor + N_NODES;                           // 50,000 i
    int*   part    = deg + N_NODES;                              // 50,000 i
    int*   bsum    = part + N_NODES;                             // 196 i
    int*   boff    = bsum + N_SCAN_BLOCKS;                       // 197 i
    float* bufs[2] = {buf0, buf1};

    const int edge_blocks = (N_EDGES + 255) / 256;
    const int norm_blocks = (N_NODES + 3) / 4;   // 4 waves / 256-thread block
    const int spmm_blocks = (N_NODES + 3) / 4;

    // ---- CSR build ----
    hipMemsetAsync(deg, 0, sizeof(int) * N_NODES, stream);
    count_deg<<<edge_blocks, 256, 0, stream>>>(adj_row, deg);
    scan_stageA<<<N_SCAN_BLOCKS, SCAN_BLK, 0, stream>>>(deg, part, bsum);
    scan_stageB<<<1, SCAN_BLK, 0, stream>>>(bsum, boff);
    scan_stageC<<<N_SCAN_BLOCKS, SCAN_BLK, 0, stream>>>(part, boff, row_ptr, cursor);
    scatter_csr<<<edge_blocks, 256, 0, stream>>>(adj_row, adj_col, adj_val,
                                                 cursor, csr_col, csr_val);

    // ---- layer 0: out = a[0] * normalize(embedding) ----
    norm_add<<<norm_blocks, 256, 0, stream>>>(embedding, a, 0, 1, out);

    const float* xcur = embedding;
    for (int l = 1; l <= 3; ++l) {
        float* y = bufs[(l - 1) & 1];
        spmm_csr<<<spmm_blocks, 256, 0, stream>>>(row_ptr, csr_col, csr_val, xcur, y);
        norm_add<<<norm_blocks, 256, 0, stream>>>(y, a, l, 0, out);
        xcur = y;
    }
}

// Round 4
// 315.303 us; speedup vs baseline: 3.6403x; 1.2905x over previous
//
#include <hip/hip_runtime.h>
#include <hip/hip_bf16.h>

#define N_NODES 50000
#define N_EDGES 800000
#define EMB 100
#define HALF_EMB 50
#define NORM_EPS 1e-12f
#define SCAN_BLK 256
#define N_SCAN_BLOCKS ((N_NODES + SCAN_BLK - 1) / SCAN_BLK)   // 196

__global__ void count_deg(const int* __restrict__ adj_row, int* __restrict__ deg) {
    int e = blockIdx.x * blockDim.x + threadIdx.x;
    if (e < N_EDGES) atomicAdd(&deg[adj_row[e]], 1);
}

__global__ void scan_stageA(const int* __restrict__ deg, int* __restrict__ part,
                            int* __restrict__ bsum) {
    __shared__ int s[SCAN_BLK];
    int t = threadIdx.x;
    int gid = blockIdx.x * SCAN_BLK + t;
    int v = (gid < N_NODES) ? deg[gid] : 0;
    s[t] = v;
    __syncthreads();
    #pragma unroll
    for (int off = 1; off < SCAN_BLK; off <<= 1) {
        int n = (t >= off) ? s[t - off] : 0;
        __syncthreads();
        s[t] += n;
        __syncthreads();
    }
    int incl = s[t];
    if (gid < N_NODES) part[gid] = incl - v;
    if (t == SCAN_BLK - 1) bsum[blockIdx.x] = incl;
}

__global__ void scan_stageB(int* __restrict__ bsum, int* __restrict__ boff) {
    __shared__ int s[SCAN_BLK];
    int t = threadIdx.x;
    int v = (t < N_SCAN_BLOCKS) ? bsum[t] : 0;
    s[t] = v;
    __syncthreads();
    #pragma unroll
    for (int off = 1; off < SCAN_BLK; off <<= 1) {
        int n = (t >= off) ? s[t - off] : 0;
        __syncthreads();
        s[t] += n;
        __syncthreads();
    }
    if (t < N_SCAN_BLOCKS) boff[t] = s[t] - v;
    if (t == N_SCAN_BLOCKS - 1) boff[N_SCAN_BLOCKS] = s[t];
}

__global__ void scan_stageC(const int* __restrict__ part, const int* __restrict__ boff,
                            int* __restrict__ row_ptr, int* __restrict__ cursor) {
    int gid = blockIdx.x * SCAN_BLK + threadIdx.x;
    if (gid < N_NODES) {
        int rp = part[gid] + boff[blockIdx.x];
        row_ptr[gid] = rp;
        cursor[gid]  = rp;
    }
    if (gid == 0) row_ptr[N_NODES] = boff[N_SCAN_BLOCKS];
}

// Pack (col, val) into one int2 stream: one 8B store on scatter, one 8B load on gather.
__global__ void scatter_csr(const int* __restrict__ adj_row, const int* __restrict__ adj_col,
                            const float* __restrict__ adj_val, int* __restrict__ cursor,
                            int2* __restrict__ csr_cv) {
    int e = blockIdx.x * blockDim.x + threadIdx.x;
    if (e < N_EDGES) {
        int r = adj_row[e];
        int p = atomicAdd(&cursor[r], 1);
        csr_cv[p] = make_int2(adj_col[e], __float_as_int(adj_val[e]));
    }
}

// Layer 0: out = a[0]*normalize(emb); also emit xb = bf16(emb) for layer-1 gather.
__global__ void norm0(const float* __restrict__ emb, const float* __restrict__ a,
                      float* __restrict__ out, __hip_bfloat162* __restrict__ xb) {
    int wave = blockIdx.x * (blockDim.x >> 6) + (threadIdx.x >> 6);
    int lane = threadIdx.x & 63;
    if (wave >= N_NODES) return;
    float2 v = make_float2(0.0f, 0.0f);
    size_t idx = (size_t)wave * HALF_EMB + lane;
    if (lane < HALF_EMB) v = ((const float2*)emb)[idx];
    float s = v.x * v.x + v.y * v.y;
    #pragma unroll
    for (int off = 32; off > 0; off >>= 1) s += __shfl_xor(s, off);
    float scale = a[0] / fmaxf(sqrtf(s), NORM_EPS);
    if (lane < HALF_EMB) {
        ((float2*)out)[idx] = make_float2(v.x * scale, v.y * scale);
        __hip_bfloat162 b;
        b.x = __float2bfloat16(v.x);
        b.y = __float2bfloat16(v.y);
        xb[idx] = b;
    }
}

// Fused SpMM (bf16 gather, fp32 accumulate) + L2-normalize + out += a[l]*row/norm.
// Writes bf16 y for the next layer's gather (yb may be null on the last layer).
__global__ void spmm_fused(const int* __restrict__ row_ptr, const int2* __restrict__ csr_cv,
                           const __hip_bfloat162* __restrict__ xb,
                           __hip_bfloat162* __restrict__ yb,
                           const float* __restrict__ a, int l,
                           float* __restrict__ out) {
    int wave = blockIdx.x * (blockDim.x >> 6) + (threadIdx.x >> 6);
    int lane = threadIdx.x & 63;
    if (wave >= N_NODES) return;
    int start = row_ptr[wave];
    int end   = row_ptr[wave + 1];
    float ax = 0.0f, ay = 0.0f;
    int e = start;
    for (; e + 3 < end; e += 4) {
        int2 cv0 = csr_cv[e];
        int2 cv1 = csr_cv[e + 1];
        int2 cv2 = csr_cv[e + 2];
        int2 cv3 = csr_cv[e + 3];
        if (lane < HALF_EMB) {
            __hip_bfloat162 p0 = xb[(size_t)cv0.x * HALF_EMB + lane];
            __hip_bfloat162 p1 = xb[(size_t)cv1.x * HALF_EMB + lane];
            __hip_bfloat162 p2 = xb[(size_t)cv2.x * HALF_EMB + lane];
            __hip_bfloat162 p3 = xb[(size_t)cv3.x * HALF_EMB + lane];
            float v0 = __int_as_float(cv0.y), v1 = __int_as_float(cv1.y);
            float v2 = __int_as_float(cv2.y), v3 = __int_as_float(cv3.y);
            ax += v0 * __bfloat162float(p0.x); ay += v0 * __bfloat162float(p0.y);
            ax += v1 * __bfloat162float(p1.x); ay += v1 * __bfloat162float(p1.y);
            ax += v2 * __bfloat162float(p2.x); ay += v2 * __bfloat162float(p2.y);
            ax += v3 * __bfloat162float(p3.x); ay += v3 * __bfloat162float(p3.y);
        }
    }
    for (; e < end; ++e) {
        int2 cv = csr_cv[e];
        if (lane < HALF_EMB) {
            __hip_bfloat162 p = xb[(size_t)cv.x * HALF_EMB + lane];
            float v = __int_as_float(cv.y);
            ax += v * __bfloat162float(p.x);
            ay += v * __bfloat162float(p.y);
        }
    }
    float s = ax * ax + ay * ay;
    #pragma unroll
    for (int off = 32; off > 0; off >>= 1) s += __shfl_xor(s, off);
    float scale = a[l] / fmaxf(sqrtf(s), NORM_EPS);
    if (lane < HALF_EMB) {
        size_t idx = (size_t)wave * HALF_EMB + lane;
        if (yb) {
            __hip_bfloat162 b;
            b.x = __float2bfloat16(ax);
            b.y = __float2bfloat16(ay);
            yb[idx] = b;
        }
        float2 cur = ((float2*)out)[idx];
        cur.x += scale * ax;
        cur.y += scale * ay;
        ((float2*)out)[idx] = cur;
    }
}

extern "C" void kernel_launch(void* const* d_in, const int* in_sizes, int n_in,
                              void* d_out, int out_size, void* d_ws, size_t ws_size,
                              hipStream_t stream) {
    const int*   adj_row   = (const int*)d_in[0];
    const int*   adj_col   = (const int*)d_in[1];
    const float* adj_val   = (const float*)d_in[2];
    const float* embedding = (const float*)d_in[3];
    const float* a         = (const float*)d_in[4];
    float* out = (float*)d_out;

    // workspace layout (8B-aligned items first)
    int2* csr_cv = (int2*)d_ws;                                    // 800,000 int2
    __hip_bfloat162* xb0 = (__hip_bfloat162*)(csr_cv + N_EDGES);   // 2,500,000
    __hip_bfloat162* xb1 = xb0 + (size_t)N_NODES * HALF_EMB;       // 2,500,000
    int* row_ptr = (int*)(xb1 + (size_t)N_NODES * HALF_EMB);       // 50,001
    int* cursor  = row_ptr + (N_NODES + 1);                        // 50,000
    int* deg     = cursor + N_NODES;                               // 50,000
    int* part    = deg + N_NODES;                                  // 50,000
    int* bsum    = part + N_NODES;                                 // 196
    int* boff    = bsum + N_SCAN_BLOCKS;                           // 197
    __hip_bfloat162* xbs[2] = {xb0, xb1};

    const int edge_blocks = (N_EDGES + 255) / 256;
    const int node_blocks = (N_NODES + 3) / 4;   // 4 waves / 256-thread block

    // ---- CSR build ----
    hipMemsetAsync(deg, 0, sizeof(int) * N_NODES, stream);
    count_deg<<<edge_blocks, 256, 0, stream>>>(adj_row, deg);
    scan_stageA<<<N_SCAN_BLOCKS, SCAN_BLK, 0, stream>>>(deg, part, bsum);
    scan_stageB<<<1, SCAN_BLK, 0, stream>>>(bsum, boff);
    scan_stageC<<<N_SCAN_BLOCKS, SCAN_BLK, 0, stream>>>(part, boff, row_ptr, cursor);
    scatter_csr<<<edge_blocks, 256, 0, stream>>>(adj_row, adj_col, adj_val,
                                                 cursor, csr_cv);

    // ---- layer 0 ----
    norm0<<<node_blocks, 256, 0, stream>>>(embedding, a, out, xb0);

    // ---- layers 1..3 fused ----
    for (int l = 1; l <= 3; ++l) {
        __hip_bfloat162* xin  = xbs[(l - 1) & 1];
        __hip_bfloat162* xout = (l < 3) ? xbs[l & 1] : (__hip_bfloat162*)nullptr;
        spmm_fused<<<node_blocks, 256, 0, stream>>>(row_ptr, csr_cv, xin, xout,
                                                    a, l, out);
    }
}

// Round 5
// 258.807 us; speedup vs baseline: 4.4350x; 1.2183x over previous
//
#include <hip/hip_runtime.h>
#include <hip/hip_bf16.h>

#define N_NODES 50000
#define N_EDGES 800000
#define EMB 100
#define HALF_EMB 50
#define NORM_EPS 1e-12f
#define BROWS 128                     // rows per bucket
#define NB ((N_NODES + BROWS - 1) / BROWS)   // 391 buckets
#define CAP 4096                      // slab capacity per bucket (avg fill ~2046)
#define EPB 4096                      // edges per partition block

// Pass 1: block-level radix partition into NB coarse buckets.
// Each block: LDS histogram -> one global atomic reserve per bucket -> write
// packed ((row<<16)|col, val_bits) into its contiguous reserved runs.
__global__ void bucket_scatter(const int* __restrict__ adj_row,
                               const int* __restrict__ adj_col,
                               const float* __restrict__ adj_val,
                               int* __restrict__ bucket_cnt,
                               int2* __restrict__ slab) {
    __shared__ int hist[NB];
    __shared__ int gbase[NB];
    __shared__ int lcur[NB];
    const int t = threadIdx.x;
    const int base_e = blockIdx.x * EPB;
    for (int i = t; i < NB; i += 256) { hist[i] = 0; lcur[i] = 0; }
    __syncthreads();
    int rows[EPB / 256];
    #pragma unroll
    for (int j = 0; j < EPB / 256; ++j) {
        int e = base_e + j * 256 + t;
        int r = (e < N_EDGES) ? adj_row[e] : -1;
        rows[j] = r;
        if (r >= 0) atomicAdd(&hist[r >> 7], 1);
    }
    __syncthreads();
    for (int i = t; i < NB; i += 256) {
        int c = hist[i];
        gbase[i] = (c > 0) ? atomicAdd(&bucket_cnt[i], c) : 0;
    }
    __syncthreads();
    #pragma unroll
    for (int j = 0; j < EPB / 256; ++j) {
        int e = base_e + j * 256 + t;
        int r = rows[j];
        if (r >= 0) {
            int b = r >> 7;
            int p = atomicAdd(&lcur[b], 1);
            unsigned rc = ((unsigned)r << 16) | (unsigned)adj_col[e];
            slab[(size_t)b * CAP + gbase[b] + p] =
                make_int2((int)rc, __float_as_int(adj_val[e]));
        }
    }
}

// Pass 2: exclusive scan of 391 bucket counts (single block of 512).
__global__ void scan_buckets(const int* __restrict__ bucket_cnt,
                             int* __restrict__ bucket_base,
                             int* __restrict__ row_ptr) {
    __shared__ int s[512];
    int t = threadIdx.x;
    int v = (t < NB) ? bucket_cnt[t] : 0;
    s[t] = v;
    __syncthreads();
    #pragma unroll
    for (int off = 1; off < 512; off <<= 1) {
        int n = (t >= off) ? s[t - off] : 0;
        __syncthreads();
        s[t] += n;
        __syncthreads();
    }
    if (t < NB) bucket_base[t] = s[t] - v;
    if (t == 0) {
        bucket_base[NB] = s[511];        // grand total (= N_EDGES)
        row_ptr[N_NODES] = N_EDGES;
    }
}

// Pass 3: per-bucket counting sort in LDS -> exact CSR + row_ptr.
// All global reads/writes are contiguous within the bucket region.
__global__ void csr_build(const int* __restrict__ bucket_cnt,
                          const int* __restrict__ bucket_base,
                          const int2* __restrict__ slab,
                          int2* __restrict__ csr_cv,
                          int* __restrict__ row_ptr) {
    __shared__ int2 eds[CAP];
    __shared__ int hist[BROWS];   // later reused as scatter cursor
    __shared__ int incl[BROWS];
    const int b = blockIdx.x, t = threadIdx.x;
    const int cnt = bucket_cnt[b];
    const int base = bucket_base[b];
    for (int i = t; i < cnt; i += 256) eds[i] = slab[(size_t)b * CAP + i];
    if (t < BROWS) hist[t] = 0;
    __syncthreads();
    for (int i = t; i < cnt; i += 256)
        atomicAdd(&hist[(int)(((unsigned)eds[i].x) >> 16) & (BROWS - 1)], 1);
    __syncthreads();
    int v = (t < BROWS) ? hist[t] : 0;
    if (t < BROWS) incl[t] = v;
    __syncthreads();
    #pragma unroll
    for (int off = 1; off < BROWS; off <<= 1) {
        int n = (t >= off && t < BROWS) ? incl[t - off] : 0;
        __syncthreads();
        if (t < BROWS) incl[t] += n;
        __syncthreads();
    }
    int ex = (t < BROWS) ? (incl[t] - v) : 0;
    __syncthreads();
    if (t < BROWS) hist[t] = ex;          // cursor init
    int gr = b * BROWS + t;
    if (t < BROWS && gr < N_NODES) row_ptr[gr] = base + ex;
    __syncthreads();
    for (int i = t; i < cnt; i += 256) {
        int2 e = eds[i];
        int l = (int)(((unsigned)e.x) >> 16) & (BROWS - 1);
        int p = atomicAdd(&hist[l], 1);
        csr_cv[base + p] = e;
    }
}

// Layer 0: out = a[0]*normalize(emb); also emit xb = bf16(emb) for layer-1 gather.
__global__ void norm0(const float* __restrict__ emb, const float* __restrict__ a,
                      float* __restrict__ out, __hip_bfloat162* __restrict__ xb) {
    int wave = blockIdx.x * (blockDim.x >> 6) + (threadIdx.x >> 6);
    int lane = threadIdx.x & 63;
    if (wave >= N_NODES) return;
    float2 v = make_float2(0.0f, 0.0f);
    size_t idx = (size_t)wave * HALF_EMB + lane;
    if (lane < HALF_EMB) v = ((const float2*)emb)[idx];
    float s = v.x * v.x + v.y * v.y;
    #pragma unroll
    for (int off = 32; off > 0; off >>= 1) s += __shfl_xor(s, off);
    float scale = a[0] / fmaxf(sqrtf(s), NORM_EPS);
    if (lane < HALF_EMB) {
        ((float2*)out)[idx] = make_float2(v.x * scale, v.y * scale);
        __hip_bfloat162 b;
        b.x = __float2bfloat16(v.x);
        b.y = __float2bfloat16(v.y);
        xb[idx] = b;
    }
}

// Fused SpMM (bf16 gather, fp32 accumulate) + L2-normalize + out += a[l]*row/norm.
__global__ void spmm_fused(const int* __restrict__ row_ptr, const int2* __restrict__ csr_cv,
                           const __hip_bfloat162* __restrict__ xb,
                           __hip_bfloat162* __restrict__ yb,
                           const float* __restrict__ a, int l,
                           float* __restrict__ out) {
    int wave = blockIdx.x * (blockDim.x >> 6) + (threadIdx.x >> 6);
    int lane = threadIdx.x & 63;
    if (wave >= N_NODES) return;
    int start = row_ptr[wave];
    int end   = row_ptr[wave + 1];
    float ax = 0.0f, ay = 0.0f;
    int e = start;
    for (; e + 3 < end; e += 4) {
        int2 cv0 = csr_cv[e];
        int2 cv1 = csr_cv[e + 1];
        int2 cv2 = csr_cv[e + 2];
        int2 cv3 = csr_cv[e + 3];
        if (lane < HALF_EMB) {
            __hip_bfloat162 p0 = xb[(size_t)(cv0.x & 0xFFFF) * HALF_EMB + lane];
            __hip_bfloat162 p1 = xb[(size_t)(cv1.x & 0xFFFF) * HALF_EMB + lane];
            __hip_bfloat162 p2 = xb[(size_t)(cv2.x & 0xFFFF) * HALF_EMB + lane];
            __hip_bfloat162 p3 = xb[(size_t)(cv3.x & 0xFFFF) * HALF_EMB + lane];
            float v0 = __int_as_float(cv0.y), v1 = __int_as_float(cv1.y);
            float v2 = __int_as_float(cv2.y), v3 = __int_as_float(cv3.y);
            ax += v0 * __bfloat162float(p0.x); ay += v0 * __bfloat162float(p0.y);
            ax += v1 * __bfloat162float(p1.x); ay += v1 * __bfloat162float(p1.y);
            ax += v2 * __bfloat162float(p2.x); ay += v2 * __bfloat162float(p2.y);
            ax += v3 * __bfloat162float(p3.x); ay += v3 * __bfloat162float(p3.y);
        }
    }
    for (; e < end; ++e) {
        int2 cv = csr_cv[e];
        if (lane < HALF_EMB) {
            __hip_bfloat162 p = xb[(size_t)(cv.x & 0xFFFF) * HALF_EMB + lane];
            float v = __int_as_float(cv.y);
            ax += v * __bfloat162float(p.x);
            ay += v * __bfloat162float(p.y);
        }
    }
    float s = ax * ax + ay * ay;
    #pragma unroll
    for (int off = 32; off > 0; off >>= 1) s += __shfl_xor(s, off);
    float scale = a[l] / fmaxf(sqrtf(s), NORM_EPS);
    if (lane < HALF_EMB) {
        size_t idx = (size_t)wave * HALF_EMB + lane;
        if (yb) {
            __hip_bfloat162 bb;
            bb.x = __float2bfloat16(ax);
            bb.y = __float2bfloat16(ay);
            yb[idx] = bb;
        }
        float2 cur = ((float2*)out)[idx];
        cur.x += scale * ax;
        cur.y += scale * ay;
        ((float2*)out)[idx] = cur;
    }
}

extern "C" void kernel_launch(void* const* d_in, const int* in_sizes, int n_in,
                              void* d_out, int out_size, void* d_ws, size_t ws_size,
                              hipStream_t stream) {
    const int*   adj_row   = (const int*)d_in[0];
    const int*   adj_col   = (const int*)d_in[1];
    const float* adj_val   = (const float*)d_in[2];
    const float* embedding = (const float*)d_in[3];
    const float* a         = (const float*)d_in[4];
    float* out = (float*)d_out;

    // workspace layout (8B-aligned items first)
    int2* slab   = (int2*)d_ws;                                    // NB*CAP int2 = 12.8 MB
    int2* csr_cv = slab + (size_t)NB * CAP;                        // 800,000 int2
    __hip_bfloat162* xb0 = (__hip_bfloat162*)(csr_cv + N_EDGES);   // 2,500,000
    __hip_bfloat162* xb1 = xb0 + (size_t)N_NODES * HALF_EMB;       // 2,500,000
    int* row_ptr     = (int*)(xb1 + (size_t)N_NODES * HALF_EMB);   // 50,001
    int* bucket_cnt  = row_ptr + (N_NODES + 1);                    // NB
    int* bucket_base = bucket_cnt + NB;                            // NB + 1
    __hip_bfloat162* xbs[2] = {xb0, xb1};

    const int node_blocks = (N_NODES + 3) / 4;   // 4 waves / 256-thread block
    const int part_blocks = (N_EDGES + EPB - 1) / EPB;  // 196

    // ---- CSR build: partition -> scan -> per-bucket sort ----
    hipMemsetAsync(bucket_cnt, 0, sizeof(int) * NB, stream);
    bucket_scatter<<<part_blocks, 256, 0, stream>>>(adj_row, adj_col, adj_val,
                                                    bucket_cnt, slab);
    scan_buckets<<<1, 512, 0, stream>>>(bucket_cnt, bucket_base, row_ptr);
    csr_build<<<NB, 256, 0, stream>>>(bucket_cnt, bucket_base, slab, csr_cv, row_ptr);

    // ---- layer 0 ----
    norm0<<<node_blocks, 256, 0, stream>>>(embedding, a, out, xb0);

    // ---- layers 1..3 fused ----
    for (int l = 1; l <= 3; ++l) {
        __hip_bfloat162* xin  = xbs[(l - 1) & 1];
        __hip_bfloat162* xout = (l < 3) ? xbs[l & 1] : (__hip_bfloat162*)nullptr;
        spmm_fused<<<node_blocks, 256, 0, stream>>>(row_ptr, csr_cv, xin, xout,
                                                    a, l, out);
    }
}